// Round 13
// baseline (15085.208 us; speedup 1.0000x reference)
//
#include <hip/hip_runtime.h>
#include <hip/hip_bf16.h>
#include <math.h>

// ---------------- problem constants ----------------
#define S_LEN 2048
#define T_LEN 2048
#define HID   1024
#define GATES 4096
#define VOCAB 50257

typedef unsigned int u32;
typedef unsigned short u16;
typedef unsigned long long ull;
typedef u32 u32x4 __attribute__((ext_vector_type(4)));
typedef float f32x4 __attribute__((ext_vector_type(4)));
typedef short s16x8 __attribute__((ext_vector_type(8)));   // bf16x8 MFMA fragment

__device__ __forceinline__ float fsig_(float x)  { return 1.0f / (1.0f + __expf(-x)); }
__device__ __forceinline__ float ftanh_(float x) { float e = __expf(2.0f * x); return 1.0f - 2.0f / (e + 1.0f); }

__device__ __forceinline__ u32 bf16rne(float x) {
  u32 u = __float_as_uint(x);
  return (u + 0x7FFFu + ((u >> 16) & 1u)) >> 16;
}
__device__ __forceinline__ float bf16tof(u32 b) { return __uint_as_float(b << 16); }

// ---- volatile-asm weight load: 4 float4 chunks at base+{0,1024,2048,3072}B ----
// Values defined by volatile asm CANNOT be rematerialized as loads -- this is
// what finally forces register residency (R10's "+v" touch failed: the IR
// loads themselves were cloned back into the loop; R11's AGPRs worked but paid
// a v_accvgpr_read per FMA, 45% VALUBusy).
__device__ __forceinline__ void wload4(const float* base, f32x4& w0, f32x4& w1,
                                       f32x4& w2, f32x4& w3) {
  asm volatile(
    "global_load_dwordx4 %0, %4, off\n\t"
    "global_load_dwordx4 %1, %4, off offset:1024\n\t"
    "global_load_dwordx4 %2, %4, off offset:2048\n\t"
    "global_load_dwordx4 %3, %4, off offset:3072\n\t"
    "s_waitcnt vmcnt(0)"
    : "=&v"(w0), "=&v"(w1), "=&v"(w2), "=&v"(w3)
    : "v"(base) : "memory");
}

// ---- software-pipelined poll of two packed 8B slots {tag(hi32), h(lo32)} ----
// Depth-2, vmcnt(2) retirement -> detection cadence ~RT/2 (R12, -0.33us/step).
__device__ __forceinline__ void pollpipe2(const ull* p0, const ull* p1, u32 want,
                                          ull& ra, ull& rb) {
  ull r0a, r0b, r1a, r1b, stmp;
  u32 par;
  const ull wantv = ((ull)want) << 32;
  asm volatile(
    "s_waitcnt vmcnt(0)\n\t"
    "global_load_dwordx2 %[r0a], %[p0], off sc0 sc1\n\t"
    "global_load_dwordx2 %[r0b], %[p1], off sc0 sc1\n\t"
    "1:\n\t"
    "global_load_dwordx2 %[r1a], %[p0], off sc0 sc1\n\t"
    "global_load_dwordx2 %[r1b], %[p1], off sc0 sc1\n\t"
    "s_waitcnt vmcnt(2)\n\t"
    "v_cmp_lt_u64 vcc, %[r0a], %[wv]\n\t"
    "s_mov_b64 %[st], vcc\n\t"
    "v_cmp_lt_u64 vcc, %[r0b], %[wv]\n\t"
    "s_or_b64 vcc, vcc, %[st]\n\t"
    "s_cbranch_vccz 2f\n\t"
    "global_load_dwordx2 %[r0a], %[p0], off sc0 sc1\n\t"
    "global_load_dwordx2 %[r0b], %[p1], off sc0 sc1\n\t"
    "s_waitcnt vmcnt(2)\n\t"
    "v_cmp_lt_u64 vcc, %[r1a], %[wv]\n\t"
    "s_mov_b64 %[st], vcc\n\t"
    "v_cmp_lt_u64 vcc, %[r1b], %[wv]\n\t"
    "s_or_b64 vcc, vcc, %[st]\n\t"
    "s_cbranch_vccz 3f\n\t"
    "s_branch 1b\n\t"
    "2:\n\t"
    "s_mov_b32 %[par], 0\n\t"
    "s_branch 4f\n\t"
    "3:\n\t"
    "s_mov_b32 %[par], 1\n\t"
    "4:\n\t"
    "s_waitcnt vmcnt(0)"
    : [r0a]"=&v"(r0a), [r0b]"=&v"(r0b), [r1a]"=&v"(r1a), [r1b]"=&v"(r1b),
      [st]"=&s"(stmp), [par]"=&s"(par)
    : [p0]"v"(p0), [p1]"v"(p1), [wv]"v"(wantv)
    : "vcc", "memory");
  ra = par ? r1a : r0a;
  rb = par ? r1b : r0b;
}

// ---- merged 4-slot pipelined poll (2 slots stream A + 2 slots stream B) ----
// One entry-drain + one pipeline instead of two sequential pollpipe2's: saves
// a serialized vmcnt(0)+RT (~0.5us) from the L1 round each step.
__device__ __forceinline__ void pollpipe4(const ull* p0, const ull* p1, u32 wantA,
                                          const ull* q0, const ull* q1, u32 wantB,
                                          ull& ra, ull& rb, ull& rc, ull& rd) {
  ull r0a, r0b, r0c, r0d, r1a, r1b, r1c, r1d, stmp;
  u32 par;
  const ull wA = ((ull)wantA) << 32;
  const ull wB = ((ull)wantB) << 32;
  asm volatile(
    "s_waitcnt vmcnt(0)\n\t"
    "global_load_dwordx2 %[r0a], %[p0], off sc0 sc1\n\t"
    "global_load_dwordx2 %[r0b], %[p1], off sc0 sc1\n\t"
    "global_load_dwordx2 %[r0c], %[q0], off sc0 sc1\n\t"
    "global_load_dwordx2 %[r0d], %[q1], off sc0 sc1\n\t"
    "1:\n\t"
    "global_load_dwordx2 %[r1a], %[p0], off sc0 sc1\n\t"
    "global_load_dwordx2 %[r1b], %[p1], off sc0 sc1\n\t"
    "global_load_dwordx2 %[r1c], %[q0], off sc0 sc1\n\t"
    "global_load_dwordx2 %[r1d], %[q1], off sc0 sc1\n\t"
    "s_waitcnt vmcnt(4)\n\t"
    "v_cmp_lt_u64 vcc, %[r0a], %[wA]\n\t"
    "s_mov_b64 %[st], vcc\n\t"
    "v_cmp_lt_u64 vcc, %[r0b], %[wA]\n\t"
    "s_or_b64 %[st], vcc, %[st]\n\t"
    "v_cmp_lt_u64 vcc, %[r0c], %[wB]\n\t"
    "s_or_b64 %[st], vcc, %[st]\n\t"
    "v_cmp_lt_u64 vcc, %[r0d], %[wB]\n\t"
    "s_or_b64 vcc, vcc, %[st]\n\t"
    "s_cbranch_vccz 2f\n\t"
    "global_load_dwordx2 %[r0a], %[p0], off sc0 sc1\n\t"
    "global_load_dwordx2 %[r0b], %[p1], off sc0 sc1\n\t"
    "global_load_dwordx2 %[r0c], %[q0], off sc0 sc1\n\t"
    "global_load_dwordx2 %[r0d], %[q1], off sc0 sc1\n\t"
    "s_waitcnt vmcnt(4)\n\t"
    "v_cmp_lt_u64 vcc, %[r1a], %[wA]\n\t"
    "s_mov_b64 %[st], vcc\n\t"
    "v_cmp_lt_u64 vcc, %[r1b], %[wA]\n\t"
    "s_or_b64 %[st], vcc, %[st]\n\t"
    "v_cmp_lt_u64 vcc, %[r1c], %[wB]\n\t"
    "s_or_b64 %[st], vcc, %[st]\n\t"
    "v_cmp_lt_u64 vcc, %[r1d], %[wB]\n\t"
    "s_or_b64 vcc, vcc, %[st]\n\t"
    "s_cbranch_vccz 3f\n\t"
    "s_branch 1b\n\t"
    "2:\n\t"
    "s_mov_b32 %[par], 0\n\t"
    "s_branch 4f\n\t"
    "3:\n\t"
    "s_mov_b32 %[par], 1\n\t"
    "4:\n\t"
    "s_waitcnt vmcnt(0)"
    : [r0a]"=&v"(r0a), [r0b]"=&v"(r0b), [r0c]"=&v"(r0c), [r0d]"=&v"(r0d),
      [r1a]"=&v"(r1a), [r1b]"=&v"(r1b), [r1c]"=&v"(r1c), [r1d]"=&v"(r1d),
      [st]"=&s"(stmp), [par]"=&s"(par)
    : [p0]"v"(p0), [p1]"v"(p1), [q0]"v"(q0), [q1]"v"(q1),
      [wA]"v"(wA), [wB]"v"(wB)
    : "vcc", "memory");
  ra = par ? r1a : r0a;
  rb = par ? r1b : r0b;
  rc = par ? r1c : r0c;
  rd = par ? r1d : r0d;
}

// ---------------- tiny helpers ----------------
__global__ void zero_f4(float4* __restrict__ p, size_t n4) {
  size_t i = (size_t)blockIdx.x * blockDim.x + threadIdx.x;
  size_t stride = (size_t)gridDim.x * blockDim.x;
  for (; i < n4; i += stride) p[i] = make_float4(0.f, 0.f, 0.f, 0.f);
}

__global__ void build_dec_tokens(const int* __restrict__ outputs, const int* __restrict__ sos,
                                 int* __restrict__ toks, int T) {
  int t = blockIdx.x * blockDim.x + threadIdx.x;
  if (t < T) toks[t] = (t == 0) ? sos[0] : outputs[t - 1];
}

// split f32 -> bf16 hi + bf16 lo (residual), RNE
__global__ void xsplit(const float* __restrict__ x, u16* __restrict__ hi,
                       u16* __restrict__ lo, int n) {
  int i = blockIdx.x * 256 + threadIdx.x;
  if (i < n) {
    float v = x[i];
    u32 h = bf16rne(v);
    hi[i] = (u16)h;
    lo[i] = (u16)bf16rne(v - bf16tof(h));
  }
}

// ---------------- split-bf16 MFMA logits GEMM (R12-proven) ----------------
__global__ __launch_bounds__(256) void gemm_logits(
    const u16* __restrict__ Xhi, const u16* __restrict__ Xlo,
    const float* __restrict__ W, const float* __restrict__ b,
    float* __restrict__ C, int M, int N, int K)
{
  __shared__ u16 Bhi[64][40];
  __shared__ u16 Blo[64][40];
  const int tid = threadIdx.x;
  const int wv  = tid >> 6;
  const int l   = tid & 63;
  const int l15 = l & 15;
  const int kro = (l >> 4) * 8;
  const int m0  = blockIdx.y * 128;
  const int n0  = blockIdx.x * 64;
  const int srow = tid >> 2;
  const int skp  = (tid & 3) * 8;

  f32x4 acc[2][4] = {};

  for (int k0 = 0; k0 < K; k0 += 32) {
    float w[8] = {0.f};
    {
      int wr = n0 + srow;
      if (wr < N) {
        const float4 a = *(const float4*)(W + (size_t)wr * K + k0 + skp);
        const float4 c = *(const float4*)(W + (size_t)wr * K + k0 + skp + 4);
        w[0] = a.x; w[1] = a.y; w[2] = a.z; w[3] = a.w;
        w[4] = c.x; w[5] = c.y; w[6] = c.z; w[7] = c.w;
      }
    }
    __syncthreads();
#pragma unroll
    for (int e = 0; e < 8; ++e) {
      u32 h = bf16rne(w[e]);
      Bhi[srow][skp + e] = (u16)h;
      Blo[srow][skp + e] = (u16)bf16rne(w[e] - bf16tof(h));
    }
    __syncthreads();

    const size_t xoff0 = (size_t)(m0 + wv * 32 + l15) * K + k0 + kro;
    const size_t xoff1 = xoff0 + (size_t)16 * K;
    s16x8 ah0 = *(const s16x8*)(Xhi + xoff0);
    s16x8 al0 = *(const s16x8*)(Xlo + xoff0);
    s16x8 ah1 = *(const s16x8*)(Xhi + xoff1);
    s16x8 al1 = *(const s16x8*)(Xlo + xoff1);
#pragma unroll
    for (int tn = 0; tn < 4; ++tn) {
      s16x8 bh = *(const s16x8*)&Bhi[tn * 16 + l15][kro];
      s16x8 bl = *(const s16x8*)&Blo[tn * 16 + l15][kro];
      acc[0][tn] = __builtin_amdgcn_mfma_f32_16x16x32_bf16(ah0, bh, acc[0][tn], 0, 0, 0);
      acc[0][tn] = __builtin_amdgcn_mfma_f32_16x16x32_bf16(al0, bh, acc[0][tn], 0, 0, 0);
      acc[0][tn] = __builtin_amdgcn_mfma_f32_16x16x32_bf16(ah0, bl, acc[0][tn], 0, 0, 0);
      acc[1][tn] = __builtin_amdgcn_mfma_f32_16x16x32_bf16(ah1, bh, acc[1][tn], 0, 0, 0);
      acc[1][tn] = __builtin_amdgcn_mfma_f32_16x16x32_bf16(al1, bh, acc[1][tn], 0, 0, 0);
      acc[1][tn] = __builtin_amdgcn_mfma_f32_16x16x32_bf16(ah1, bl, acc[1][tn], 0, 0, 0);
    }
  }

#pragma unroll
  for (int tm = 0; tm < 2; ++tm)
#pragma unroll
    for (int tn = 0; tn < 4; ++tn) {
      int n = n0 + tn * 16 + l15;
      if (n < N) {
        float bias = b[n];
#pragma unroll
        for (int r = 0; r < 4; ++r) {
          int m = m0 + wv * 32 + tm * 16 + (l >> 4) * 4 + r;
          C[(size_t)m * N + n] = acc[tm][tn][r] + bias;
        }
      }
    }
}

// ---------------- fused 2-layer persistent LSTM ----------------
// 256 WGs x 512 threads (1 WG/CU). wg<128 layer 0 (x = embedding rows, LDS
// double-buffer prefetch); wg>=128 layer 1 (x = L0 h, 1-step skew).
// Decomposition: wave = 1 hidden unit (8 units/WG); lane owns the same 32 cols
// (8 float4 chunks of [x,h]) for all 4 gate rows -> 64KB LDS/WG-step (4x less
// than 16-lane/row) with each chunk reused across rows. Weights: 128 f32/lane
// loaded via VOLATILE-ASM global loads (non-rematerializable => genuinely
// register-resident; 256-VGPR budget at (512,1)). Epilogue fully in-wave:
// 6-level xor-reduce per gate row, all lanes compute gates, lane 0 publishes.
// Exchange: write-once packed 8B slots {tag=t+1 (hi32), f32 h (lo32)};
// L0 polls s0 via pollpipe2; L1 polls s0+s1 merged via pollpipe4.
__global__ __launch_bounds__(512, 1) void lstm2(
    const float* __restrict__ emb,  const int* __restrict__ toks,
    const float* __restrict__ Wi0,  const float* __restrict__ Wh0,
    const float* __restrict__ bi0,  const float* __restrict__ bh0,
    const float* __restrict__ Wi1,  const float* __restrict__ Wh1,
    const float* __restrict__ bi1,  const float* __restrict__ bh1,
    const float* __restrict__ h00,  const float* __restrict__ c00,
    const float* __restrict__ h01,  const float* __restrict__ c01,
    ull* __restrict__ s0, ull* __restrict__ s1,   // [T][1024] packed slots
    float* __restrict__ hf0, float* __restrict__ cf0,
    float* __restrict__ hf1, float* __restrict__ cf1,
    float* __restrict__ dec_out, int T)
{
  const int tid   = threadIdx.x;
  const int wg    = blockIdx.x;
  const bool isL0 = (wg < 128);
  const int wgl   = isL0 ? wg : wg - 128;
  const int wlane = tid & 63;
  const int unit  = tid >> 6;           // wave index == unit 0..7

  __shared__ float lds_x[2][HID];
  __shared__ float lds_h[HID];

  const float* Wi = isL0 ? Wi0 : Wi1;
  const float* Wh = isL0 ? Wh0 : Wh1;
  const float* bi = isL0 ? bi0 : bi1;
  const float* bh = isL0 ? bh0 : bh1;

  // ---- weights -> VGPRs via volatile-asm loads (non-rematerializable) ----
  // lane wlane, gate row r: cols 4*(64*(k&3)+wlane)+e; k<4 from Wi, k>=4 Wh.
  // Per (row,matrix) base = rowptr + 16B*wlane; chunks at +0/1024/2048/3072 B.
  float bias[4];
  f32x4 Wt[4][8];
#pragma unroll
  for (int r = 0; r < 4; ++r) {
    const int growr = r * HID + wgl * 8 + unit;
    bias[r] = bi[growr] + bh[growr];
    wload4(Wi + (size_t)growr * HID + 4 * wlane, Wt[r][0], Wt[r][1], Wt[r][2], Wt[r][3]);
    wload4(Wh + (size_t)growr * HID + 4 * wlane, Wt[r][4], Wt[r][5], Wt[r][6], Wt[r][7]);
  }

  float creg = (isL0 ? c00 : c01)[wgl * 8 + unit];
  {
    const float* hini = isL0 ? h00 : h01;
    if (tid < 256) ((float4*)lds_h)[tid] = ((const float4*)hini)[tid];
    if (isL0 && tid < 256) {
      int tok = toks[0];
      ((float4*)lds_x[0])[tid] = ((const float4*)(emb + (size_t)tok * HID))[tid];
    }
  }
  __syncthreads();

  ull* s_mine = isL0 ? s0 : s1;

  for (int t = 0; t < T; ++t) {
    const int cur = t & 1;

    // ---- stage step inputs (pipelined polls) ----
    if (isL0) {
      if (t > 0) {
        ull va, vb;
        pollpipe2(s0 + (size_t)(t - 1) * HID + 2 * tid,
                  s0 + (size_t)(t - 1) * HID + 2 * tid + 1, (u32)t, va, vb);
        lds_h[2 * tid]     = __uint_as_float((u32)va);
        lds_h[2 * tid + 1] = __uint_as_float((u32)vb);
      }
    } else {
      if (t == 0) {
        ull va, vb;
        pollpipe2(s0 + 2 * tid, s0 + 2 * tid + 1, 1u, va, vb);
        lds_x[0][2 * tid]     = __uint_as_float((u32)va);
        lds_x[0][2 * tid + 1] = __uint_as_float((u32)vb);
      } else {
        ull va, vb, vc, vd;
        pollpipe4(s0 + (size_t)t * HID + 2 * tid,
                  s0 + (size_t)t * HID + 2 * tid + 1, (u32)(t + 1),
                  s1 + (size_t)(t - 1) * HID + 2 * tid,
                  s1 + (size_t)(t - 1) * HID + 2 * tid + 1, (u32)t,
                  va, vb, vc, vd);
        lds_x[0][2 * tid]     = __uint_as_float((u32)va);
        lds_x[0][2 * tid + 1] = __uint_as_float((u32)vb);
        lds_h[2 * tid]        = __uint_as_float((u32)vc);
        lds_h[2 * tid + 1]    = __uint_as_float((u32)vd);
      }
    }
    __syncthreads();

    // L0: prefetch x_{t+1} after the poll barrier (retires under compute)
    if (isL0 && tid < 256 && t + 1 < T) {
      int tok = toks[t + 1];
      ((float4*)lds_x[cur ^ 1])[tid] = ((const float4*)(emb + (size_t)tok * HID))[tid];
    }

    // ---- gather 8 chunks (4 x, 4 h) once; reuse across 4 gate rows ----
    const float* xbuf = isL0 ? lds_x[cur] : lds_x[0];
    float4 xh[8];
#pragma unroll
    for (int k = 0; k < 4; ++k) xh[k]     = ((const float4*)xbuf)[64 * k + wlane];
#pragma unroll
    for (int k = 0; k < 4; ++k) xh[4 + k] = ((const float4*)lds_h)[64 * k + wlane];

    // ---- 4 gate rows x 32 cols: 128 FMAs, weights from VGPRs ----
    float sr[4];
#pragma unroll
    for (int r = 0; r < 4; ++r) {
      float a0 = 0.f, a1 = 0.f, a2 = 0.f, a3 = 0.f;
#pragma unroll
      for (int k = 0; k < 8; ++k) {
        a0 = fmaf(Wt[r][k].x, xh[k].x, a0);
        a1 = fmaf(Wt[r][k].y, xh[k].y, a1);
        a2 = fmaf(Wt[r][k].z, xh[k].z, a2);
        a3 = fmaf(Wt[r][k].w, xh[k].w, a3);
      }
      sr[r] = (a0 + a1) + (a2 + a3);
    }

    // ---- full-wave reduce per row; every lane gets all 4 gate sums ----
#pragma unroll
    for (int r = 0; r < 4; ++r) {
      float v = sr[r];
      v += __shfl_xor(v, 1);
      v += __shfl_xor(v, 2);
      v += __shfl_xor(v, 4);
      v += __shfl_xor(v, 8);
      v += __shfl_xor(v, 16);
      v += __shfl_xor(v, 32);
      sr[r] = v + bias[r];
    }

    // ---- in-wave gate epilogue (0=i 1=f 2=g 3=o) + lane-0 publish ----
    creg = fsig_(sr[1]) * creg + fsig_(sr[0]) * ftanh_(sr[2]);
    const float h = fsig_(sr[3]) * ftanh_(creg);
    if (wlane == 0) {
      const int col = wgl * 8 + unit;
      const ull pk = ((ull)(u32)(t + 1) << 32) | (ull)__float_as_uint(h);
      __hip_atomic_store(&s_mine[(size_t)t * HID + col], pk,
                         __ATOMIC_RELAXED, __HIP_MEMORY_SCOPE_AGENT);
      if (!isL0 && dec_out) dec_out[(size_t)t * HID + col] = h;
      if (t == T - 1) {
        if (isL0) { if (hf0) hf0[col] = h; if (cf0) cf0[col] = creg; }
        else      { if (hf1) hf1[col] = h; if (cf1) cf1[col] = creg; }
      }
    }
    __syncthreads();   // LDS reuse: next step's staging must not race live reads
  }
}

// ---------------- launch ----------------
extern "C" void kernel_launch(void* const* d_in, const int* in_sizes, int n_in,
                              void* d_out, int out_size, void* d_ws, size_t ws_size,
                              hipStream_t stream) {
  const int*   inputs  = (const int*)d_in[0];
  const int*   outputs = (const int*)d_in[1];
  const int*   sos     = (const int*)d_in[2];
  const float* enc_emb = (const float*)d_in[3];
  const float* dec_emb = (const float*)d_in[4];
  const float* enc_Wih = (const float*)d_in[5];
  const float* enc_Whh = (const float*)d_in[6];
  const float* enc_bih = (const float*)d_in[7];
  const float* enc_bhh = (const float*)d_in[8];
  const float* dec_Wih = (const float*)d_in[9];
  const float* dec_Whh = (const float*)d_in[10];
  const float* dec_bih = (const float*)d_in[11];
  const float* dec_bhh = (const float*)d_in[12];
  const float* lin_W   = (const float*)d_in[13];
  const float* lin_b   = (const float*)d_in[14];

  float* out = (float*)d_out;
  // d_out scratch: 4 packed streams (16 MB each), all dead before logits GEMM.
  ull* s0e = (ull*)d_out;
  ull* s1e = s0e + 2097152;
  ull* s0d = s1e + 2097152;
  ull* s1d = s0d + 2097152;

  char* ws = (char*)d_ws;
  float* zerosv = (float*)(ws + 0);
  float* hf0    = (float*)(ws + 4096);
  float* cf0    = (float*)(ws + 8192);
  float* hf1    = (float*)(ws + 12288);
  float* cf1    = (float*)(ws + 16384);
  int*   dtoks  = (int*)(ws + 20480);
  float* B2     = (float*)(ws + ((size_t)1 << 20));    // 8 MB: dec_out f32
  u16*   Xhi    = (u16*)(ws + ((size_t)10 << 20));     // 4 MB
  u16*   Xlo    = (u16*)(ws + ((size_t)15 << 20));     // 4 MB

  const size_t WOFF = (size_t)GATES * HID;

  // zero stream tags (64 MB in d_out) + zeros vector; every call (graph replay)
  zero_f4<<<2048, 256, 0, stream>>>((float4*)d_out, 4194304);
  zero_f4<<<1, 256, 0, stream>>>((float4*)zerosv, 256);
  build_dec_tokens<<<8, 256, 0, stream>>>(outputs, sos, dtoks, T_LEN);

  // encoder: both layers, fused Wi@x, layer-pipelined
  lstm2<<<256, 512, 0, stream>>>(
      enc_emb, inputs,
      enc_Wih, enc_Whh, enc_bih, enc_bhh,
      enc_Wih + WOFF, enc_Whh + WOFF, enc_bih + GATES, enc_bhh + GATES,
      zerosv, zerosv, zerosv, zerosv,
      s0e, s1e, hf0, cf0, hf1, cf1, nullptr, S_LEN);

  // decoder: init from encoder finals; layer-1 h also written plain to B2
  lstm2<<<256, 512, 0, stream>>>(
      dec_emb, dtoks,
      dec_Wih, dec_Whh, dec_bih, dec_bhh,
      dec_Wih + WOFF, dec_Whh + WOFF, dec_bih + GATES, dec_bhh + GATES,
      hf0, cf0, hf1, cf1,
      s0d, s1d, nullptr, nullptr, nullptr, nullptr, B2, T_LEN);

  // logits: split X to bf16 hi/lo, then 3-term split-bf16 MFMA GEMM
  xsplit<<<(T_LEN * HID + 255) / 256, 256, 0, stream>>>(B2, Xhi, Xlo, T_LEN * HID);
  dim3 gemmV_grid((VOCAB + 63) / 64, T_LEN / 128);
  gemm_logits<<<gemmV_grid, 256, 0, stream>>>(Xhi, Xlo, lin_W, lin_b, out,
                                              T_LEN, VOCAB, HID);
}